// Round 1
// baseline (295.416 us; speedup 1.0000x reference)
//
#include <hip/hip_runtime.h>

// score[i] = sigmoid(logits[u[i], v[i]])
// Elementwise sigmoid commutes with the gather, so we skip the full
// [V,V] sigmoid the reference materializes and only touch B elements.
__global__ void gather_sigmoid_kernel(const int* __restrict__ u,
                                      const int* __restrict__ v,
                                      const float* __restrict__ logits,
                                      float* __restrict__ out,
                                      int B, int V) {
    int i = blockIdx.x * blockDim.x + threadIdx.x;
    if (i < B) {
        int ui = u[i];
        int vi = v[i];
        // V=8192, ui<8192 -> max flat index 67,108,863 < 2^31, int math is safe,
        // but use long long for robustness.
        float x = logits[(long long)ui * (long long)V + (long long)vi];
        out[i] = 1.0f / (1.0f + __expf(-x));
    }
}

extern "C" void kernel_launch(void* const* d_in, const int* in_sizes, int n_in,
                              void* d_out, int out_size, void* d_ws, size_t ws_size,
                              hipStream_t stream) {
    const int* u = (const int*)d_in[0];
    const int* v = (const int*)d_in[1];
    const float* logits = (const float*)d_in[2];
    float* out = (float*)d_out;

    int B = in_sizes[0];          // 16384
    // logits is [V, V]; in_sizes[2] = V*V
    int V = 1;
    {
        long long n = (long long)in_sizes[2];
        // integer sqrt for perfect square V*V (V=8192 expected)
        long long r = 1;
        while (r * r < n) r <<= 1;       // power-of-two V in this problem
        if (r * r != n) {                 // fallback: linear adjust (not expected)
            r = (long long)(sqrt((double)n) + 0.5);
        }
        V = (int)r;
    }

    const int block = 256;
    const int grid = (B + block - 1) / block;
    gather_sigmoid_kernel<<<grid, block, 0, stream>>>(u, v, logits, out, B, V);
}